// Round 16
// baseline (63.896 us; speedup 1.0000x reference)
//
#include <hip/hip_runtime.h>
#include <hip/hip_bf16.h>

#define N 1024
#define D 128
#define LEAK 0.2f

#define MROWS 4          // i-rows per mega block
#define JSPLIT 4         // j-range splits (merged via atomicAdd)
#define JQ (N / JSPLIT)  // 256 j per block

// workspace layout (float offsets)
#define OFF_W2T  0
#define OFF_WPD  16384
#define OFF_WUT  16512
#define OFF_S1   16640
#define OFF_S2   17664
#define OFF_BASE 18688

// ---------------------------------------------------------------------------
// K_A: prep + base v4 = round-14 known-good + out zeroing (blocks < 128).
__global__ __launch_bounds__(256) void prep_base_kernel(
    const float* __restrict__ W, const float* __restrict__ W1,
    const float* __restrict__ W2, const float* __restrict__ a,
    const float* __restrict__ h, const float* __restrict__ b1,
    float* __restrict__ W2t, float* __restrict__ wpd, float* __restrict__ wut,
    float* __restrict__ s1, float* __restrict__ s2, float* __restrict__ base,
    float* __restrict__ out) {
    __shared__ float pool[4160];
    __shared__ float red[4], red2[4];
    int b = blockIdx.x, tid = threadIdx.x;
    if (b < 128) {
        // zero out[] so mega can atomicAdd (128*256 float4 = 512KB exactly)
        ((float4*)out)[b * 256 + tid] = make_float4(0.f, 0.f, 0.f, 0.f);
    }
    if (b < 512) {
        float* hl  = pool;          // [2][128]
        float* whl = pool + 256;    // [2][128]
        int i0 = b * 2;
        if (tid < 64) ((float4*)hl)[tid] = ((const float4*)(h + i0 * D))[tid];
        __syncthreads();
        int r = tid >> 7, l = tid & 127;
        float u = 0.f;
        #pragma unroll 8
        for (int q = 0; q < D; q += 4) {
            float4 hq = *(const float4*)&hl[r * D + q];
            float4 wq = *(const float4*)&W[l * D + q];
            u = fmaf(hq.x, wq.x, u); u = fmaf(hq.y, wq.y, u);
            u = fmaf(hq.z, wq.z, u); u = fmaf(hq.w, wq.w, u);
        }
        whl[r * D + l] = u;
        __syncthreads();
        {
            int w = tid >> 6, l63 = tid & 63;
            int row = w >> 1, half = w & 1;
            float wh = whl[row * D + half * 64 + l63];
            float p1 = wh * a[half * 64 + l63];
            float p2 = wh * a[D + half * 64 + l63];
            #pragma unroll
            for (int off = 32; off > 0; off >>= 1) {
                p1 += __shfl_xor(p1, off);
                p2 += __shfl_xor(p2, off);
            }
            if (l63 == 0) { red[w] = p1; red2[w] = p2; }
        }
        __syncthreads();
        if (tid < 2) {
            s1[i0 + tid] = red[2 * tid] + red[2 * tid + 1];
            s2[i0 + tid] = red2[2 * tid] + red2[2 * tid + 1];
        }
        float acc = b1[l];
        #pragma unroll 8
        for (int q = 0; q < D; q += 2) {
            float2 wh2 = *(const float2*)&whl[r * D + q];
            float2 x = *(const float2*)&W1[l * (D + 2) + q];
            acc = fmaf(wh2.x, x.x, acc);
            acc = fmaf(wh2.y, x.y, acc);
        }
        base[(i0 + r) * D + l] = acc;
    } else if (b < 516) {
        int kbase = 32 * (b - 512);
        #pragma unroll
        for (int p = 0; p < 16; p++) {
            int idx = tid + p * 256;
            int rd = idx >> 5, cc = idx & 31;
            pool[cc * 129 + rd] = W2[rd * D + kbase + cc];
        }
        __syncthreads();
        #pragma unroll
        for (int p = 0; p < 16; p++) {
            int idx = tid + p * 256;
            int kl = idx >> 7, dd = idx & 127;
            W2t[(kbase + kl) * D + dd] = pool[kl * 129 + dd];
        }
    } else if (b == 516) {
        if (tid < 128) wpd[tid] = W1[tid * (D + 2) + D];
        else           wut[tid - 128] = W1[(tid - 128) * (D + 2) + D + 1];
    }
}

// ---------------------------------------------------------------------------
// K_B: mega v9 — 1024 blocks x 512 thr (4 blocks/CU = 8 waves/SIMD).
//   Block b: rows i0 = (b>>2)*4, j-quarter jbase = (b&3)*256.
//   Alpha: full-row stats (v7's verified code), al stored for own quarter.
//   Main: 16 groups x 32 lanes, 16 steps over the quarter; base read = full
//   512B row per group (coalesced). Base L2 traffic 128MB (half of v5).
//   Epilogue: fold, racc, partial t @ W2t, atomicAdd into out.
__global__ __launch_bounds__(512, 8) void mega_kernel(
    const float* __restrict__ base, const float* __restrict__ s1,
    const float* __restrict__ s2, const int* __restrict__ adj,
    const float* __restrict__ pd, const float* __restrict__ ut,
    const float* __restrict__ wpd, const float* __restrict__ wut,
    const float* __restrict__ W2t, const float* __restrict__ b2,
    float* __restrict__ out) {
    __shared__ float al[MROWS][JQ];       // 4KB alpha (own quarter)
    __shared__ float racc[8][MROWS][D];   // 16KB wave partials
    __shared__ float red[8], red2[8], gsum[MROWS];
    __shared__ float tl[MROWS][D];        // 2KB

    const int tid = threadIdx.x;          // 0..511
    const int i0 = (blockIdx.x >> 2) * MROWS;
    const int jbase = (blockIdx.x & 3) * JQ;

    // ---- phase 0: alpha stats over FULL row (v7 code); al for own quarter ----
    {
        int r = tid >> 7;
        int i = i0 + r;
        int jb = (tid & 127) * 8;
        float s1i = s1[i];
        float4 sa = *(const float4*)&s2[jb];
        float4 sb = *(const float4*)&s2[jb + 4];
        int4 ma = *(const int4*)&adj[i * N + jb];
        int4 mb = *(const int4*)&adj[i * N + jb + 4];
        float e[8]; int mm[8];
        e[0]=s1i+sa.x; e[1]=s1i+sa.y; e[2]=s1i+sa.z; e[3]=s1i+sa.w;
        e[4]=s1i+sb.x; e[5]=s1i+sb.y; e[6]=s1i+sb.z; e[7]=s1i+sb.w;
        mm[0]=ma.x; mm[1]=ma.y; mm[2]=ma.z; mm[3]=ma.w;
        mm[4]=mb.x; mm[5]=mb.y; mm[6]=mb.z; mm[7]=mb.w;
        float mx = -3e38f;
        #pragma unroll
        for (int q = 0; q < 8; q++) {
            e[q] = e[q] > 0.f ? e[q] : LEAK * e[q];
            if (mm[q] > 0) mx = fmaxf(mx, e[q]);
        }
        #pragma unroll
        for (int off = 32; off > 0; off >>= 1) mx = fmaxf(mx, __shfl_xor(mx, off));
        int wid = tid >> 6, lane = tid & 63;
        if (lane == 0) red[wid] = mx;
        __syncthreads();
        mx = fmaxf(red[2 * r], red[2 * r + 1]);
        float ev[8]; float sum = 0.f;
        #pragma unroll
        for (int q = 0; q < 8; q++) {
            ev[q] = (mm[q] > 0) ? __expf(e[q] - mx) : 0.f;
            sum += ev[q];
        }
        #pragma unroll
        for (int off = 32; off > 0; off >>= 1) sum += __shfl_xor(sum, off);
        if (lane == 0) red2[wid] = sum;
        __syncthreads();
        sum = red2[2 * r] + red2[2 * r + 1];
        float inv = sum > 0.f ? 1.f / sum : 0.f;
        if (jb >= jbase && jb < jbase + JQ) {
            *(float4*)&al[r][jb - jbase]     = make_float4(ev[0]*inv, ev[1]*inv, ev[2]*inv, ev[3]*inv);
            *(float4*)&al[r][jb - jbase + 4] = make_float4(ev[4]*inv, ev[5]*inv, ev[6]*inv, ev[7]*inv);
        }
        if ((tid & 127) == 0) gsum[r] = sum;
    }
    __syncthreads();   // al + gsum visible; no further barriers until epilogue

    const int l32 = tid & 31, g = tid >> 5;       // 16 groups x 32 lanes
    const int k0 = l32 * 4;
    const float4 wp = *(const float4*)&wpd[k0];
    const float4 wu = *(const float4*)&wut[k0];

    const float* pdb = pd + (size_t)i0 * N;
    const float* utb = ut + (size_t)i0 * N;

    float4 acc[MROWS] = {};

    #pragma unroll 2
    for (int c = 0; c < 16; c++) {
        int jl = c * 16 + g;                      // local j in [0, 256)
        int j = jbase + jl;
        float4 b0 = *(const float4*)&base[j * D + k0];
        #pragma unroll
        for (int r = 0; r < MROWS; r++) {
            float spd = pdb[r * N + j];
            float sut = utb[r * N + j];
            float sal = al[r][jl];
            float v;
            v = fmaxf(fmaf(spd, wp.x, fmaf(sut, wu.x, b0.x)), 0.f); acc[r].x = fmaf(sal, v, acc[r].x);
            v = fmaxf(fmaf(spd, wp.y, fmaf(sut, wu.y, b0.y)), 0.f); acc[r].y = fmaf(sal, v, acc[r].y);
            v = fmaxf(fmaf(spd, wp.z, fmaf(sut, wu.z, b0.z)), 0.f); acc[r].z = fmaf(sal, v, acc[r].z);
            v = fmaxf(fmaf(spd, wp.w, fmaf(sut, wu.w, b0.w)), 0.f); acc[r].w = fmaf(sal, v, acc[r].w);
        }
    }

    // ---- fold the wave's two groups (lanes l <-> l^32 share k0) ----
    #pragma unroll
    for (int r = 0; r < MROWS; r++) {
        acc[r].x += __shfl_xor(acc[r].x, 32);
        acc[r].y += __shfl_xor(acc[r].y, 32);
        acc[r].z += __shfl_xor(acc[r].z, 32);
        acc[r].w += __shfl_xor(acc[r].w, 32);
    }
    {
        int w = tid >> 6, lane = tid & 63;
        if (lane < 32) {
            #pragma unroll
            for (int r = 0; r < MROWS; r++)
                *(float4*)&racc[w][r][k0] = acc[r];
        }
    }
    __syncthreads();
    {
        int rr = tid >> 7, k = tid & 127;
        float v = 0.f;
        #pragma unroll
        for (int w = 0; w < 8; w++) v += racc[w][rr][k];
        tl[rr][k] = v;
    }
    __syncthreads();
    // ---- partial GEMM + atomic merge: out[i][d] += t_part @ W2t (+gate*b2) ----
    {
        int rr = tid >> 7, d = tid & 127;
        float acc2 = (jbase == 0 && gsum[rr] > 0.f) ? b2[d] : 0.f;
        #pragma unroll 8
        for (int k = 0; k < D; k++)
            acc2 = fmaf(tl[rr][k], W2t[k * D + d], acc2);
        atomicAdd(&out[(i0 + rr) * D + d], acc2);
    }
}

// ---------------------------------------------------------------------------
extern "C" void kernel_launch(void* const* d_in, const int* in_sizes, int n_in,
                              void* d_out, int out_size, void* d_ws, size_t ws_size,
                              hipStream_t stream) {
    (void)in_sizes; (void)n_in; (void)out_size; (void)ws_size;
    const float* h   = (const float*)d_in[0];
    const int*   adj = (const int*)d_in[1];
    const float* pd  = (const float*)d_in[2];
    const float* ut  = (const float*)d_in[3];
    const float* W   = (const float*)d_in[4];
    const float* a   = (const float*)d_in[5];
    const float* W1  = (const float*)d_in[6];
    const float* b1  = (const float*)d_in[7];
    const float* W2  = (const float*)d_in[8];
    const float* b2  = (const float*)d_in[9];
    float* out = (float*)d_out;
    float* ws = (float*)d_ws;

    float* W2t   = ws + OFF_W2T;
    float* wpd   = ws + OFF_WPD;
    float* wut   = ws + OFF_WUT;
    float* s1    = ws + OFF_S1;
    float* s2    = ws + OFF_S2;
    float* baseb = ws + OFF_BASE;

    prep_base_kernel<<<517, 256, 0, stream>>>(W, W1, W2, a, h, b1,
                                              W2t, wpd, wut, s1, s2, baseb, out);
    mega_kernel<<<(N / MROWS) * JSPLIT, 512, 0, stream>>>(baseb, s1, s2, adj, pd, ut,
                                                          wpd, wut, W2t, b2, out);
}

// Round 17
// 40.002 us; speedup vs baseline: 1.5973x; 1.5973x over previous
//
#include <hip/hip_runtime.h>
#include <hip/hip_bf16.h>

#define N 1024
#define D 128
#define LEAK 0.2f

#define MROWS 2          // i-rows per mega block

// workspace layout (float offsets)
#define OFF_W2T  0
#define OFF_WPD  16384
#define OFF_WUT  16512
#define OFF_S1   16640
#define OFF_S2   17664
#define OFF_BASE 18688

// ---------------------------------------------------------------------------
// K_A: prep + base, v3 (byte-identical to round 14 — known-good).
__global__ __launch_bounds__(256) void prep_base_kernel(
    const float* __restrict__ W, const float* __restrict__ W1,
    const float* __restrict__ W2, const float* __restrict__ a,
    const float* __restrict__ h, const float* __restrict__ b1,
    float* __restrict__ W2t, float* __restrict__ wpd, float* __restrict__ wut,
    float* __restrict__ s1, float* __restrict__ s2, float* __restrict__ base) {
    __shared__ float pool[4160];
    __shared__ float red[4], red2[4];
    int b = blockIdx.x, tid = threadIdx.x;
    if (b < 512) {
        float* hl  = pool;          // [2][128]
        float* whl = pool + 256;    // [2][128]
        int i0 = b * 2;
        if (tid < 64) ((float4*)hl)[tid] = ((const float4*)(h + i0 * D))[tid];
        __syncthreads();
        int r = tid >> 7, l = tid & 127;
        float u = 0.f;
        #pragma unroll 8
        for (int q = 0; q < D; q += 4) {
            float4 hq = *(const float4*)&hl[r * D + q];
            float4 wq = *(const float4*)&W[l * D + q];
            u = fmaf(hq.x, wq.x, u); u = fmaf(hq.y, wq.y, u);
            u = fmaf(hq.z, wq.z, u); u = fmaf(hq.w, wq.w, u);
        }
        whl[r * D + l] = u;
        __syncthreads();
        {
            int w = tid >> 6, l63 = tid & 63;
            int row = w >> 1, half = w & 1;
            float wh = whl[row * D + half * 64 + l63];
            float p1 = wh * a[half * 64 + l63];
            float p2 = wh * a[D + half * 64 + l63];
            #pragma unroll
            for (int off = 32; off > 0; off >>= 1) {
                p1 += __shfl_xor(p1, off);
                p2 += __shfl_xor(p2, off);
            }
            if (l63 == 0) { red[w] = p1; red2[w] = p2; }
        }
        __syncthreads();
        if (tid < 2) {
            s1[i0 + tid] = red[2 * tid] + red[2 * tid + 1];
            s2[i0 + tid] = red2[2 * tid] + red2[2 * tid + 1];
        }
        float acc = b1[l];
        #pragma unroll 8
        for (int q = 0; q < D; q += 2) {
            float2 wh2 = *(const float2*)&whl[r * D + q];
            float2 x = *(const float2*)&W1[l * (D + 2) + q];
            acc = fmaf(wh2.x, x.x, acc);
            acc = fmaf(wh2.y, x.y, acc);
        }
        base[(i0 + r) * D + l] = acc;
    } else if (b < 516) {
        int kbase = 32 * (b - 512);
        #pragma unroll
        for (int p = 0; p < 16; p++) {
            int idx = tid + p * 256;
            int rd = idx >> 5, cc = idx & 31;
            pool[cc * 129 + rd] = W2[rd * D + kbase + cc];
        }
        __syncthreads();
        #pragma unroll
        for (int p = 0; p < 16; p++) {
            int idx = tid + p * 256;
            int kl = idx >> 7, dd = idx & 127;
            W2t[(kbase + kl) * D + dd] = pool[kl * 129 + dd];
        }
    } else {
        if (tid < 128) wpd[tid] = W1[tid * (D + 2) + D];
        else           wut[tid - 128] = W1[(tid - 128) * (D + 2) + D + 1];
    }
}

// ---------------------------------------------------------------------------
// K_B: mega v10 = v5 (R11/R14 best-known) + pd/ut staged in LDS once.
//   512 blocks x 1024 thr, MROWS=2, 8 waves/SIMD. LDS 41KB -> 2 blocks/CU.
//   Main loop global traffic: only 2x base b128 per chunk; pd/ut/al are LDS
//   broadcasts. No barriers in the loop.
__global__ __launch_bounds__(1024, 8) void mega_kernel(
    const float* __restrict__ base, const float* __restrict__ s1,
    const float* __restrict__ s2, const int* __restrict__ adj,
    const float* __restrict__ pd, const float* __restrict__ ut,
    const float* __restrict__ wpd, const float* __restrict__ wut,
    const float* __restrict__ W2t, const float* __restrict__ b2,
    float* __restrict__ out) {
    __shared__ float al[MROWS][N];         // 8KB alpha
    __shared__ float pdl[MROWS][N];        // 8KB staged pd rows
    __shared__ float utl[MROWS][N];        // 8KB staged ut rows
    __shared__ float racc[16][MROWS][D];   // 16KB wave partials
    __shared__ float red[16], red2[16], gsum[MROWS];
    __shared__ float tl[MROWS][D];         // 1KB

    const int tid = threadIdx.x;           // 0..1023
    const int i0 = blockIdx.x * MROWS;
    const float* pdb = pd + (size_t)i0 * N;
    const float* utb = ut + (size_t)i0 * N;

    // ---- stage pd/ut rows into LDS (coalesced float4); alpha's final
    //      barrier makes them visible before the main loop ----
    {
        int half = tid >> 9, idx = tid & 511;    // 512 float4 = 2 rows x 1024
        const float* src = half ? utb : pdb;
        float* dst = half ? &utl[0][0] : &pdl[0][0];
        ((float4*)dst)[idx] = ((const float4*)src)[idx];
    }

    // ---- phase 0: alpha (row r <-> 512 threads = waves 8r..8r+7) ----
    {
        int r = tid >> 9;
        int i = i0 + r;
        int jb = (tid & 511) * 2;
        float s1i = s1[i];
        float2 sa = *(const float2*)&s2[jb];
        int2 ma = *(const int2*)&adj[i * N + jb];
        float e[2]; int mm[2];
        e[0] = s1i + sa.x; e[1] = s1i + sa.y;
        mm[0] = ma.x; mm[1] = ma.y;
        float mx = -3e38f;
        #pragma unroll
        for (int q = 0; q < 2; q++) {
            e[q] = e[q] > 0.f ? e[q] : LEAK * e[q];
            if (mm[q] > 0) mx = fmaxf(mx, e[q]);
        }
        #pragma unroll
        for (int off = 32; off > 0; off >>= 1) mx = fmaxf(mx, __shfl_xor(mx, off));
        int wid = tid >> 6, lane = tid & 63;
        if (lane == 0) red[wid] = mx;
        __syncthreads();
        {
            float m0 = fmaxf(fmaxf(red[8 * r], red[8 * r + 1]),
                             fmaxf(red[8 * r + 2], red[8 * r + 3]));
            float m1 = fmaxf(fmaxf(red[8 * r + 4], red[8 * r + 5]),
                             fmaxf(red[8 * r + 6], red[8 * r + 7]));
            mx = fmaxf(m0, m1);
        }
        float ev[2]; float sum = 0.f;
        #pragma unroll
        for (int q = 0; q < 2; q++) {
            ev[q] = (mm[q] > 0) ? __expf(e[q] - mx) : 0.f;
            sum += ev[q];
        }
        #pragma unroll
        for (int off = 32; off > 0; off >>= 1) sum += __shfl_xor(sum, off);
        if (lane == 0) red2[wid] = sum;
        __syncthreads();
        sum = red2[8 * r] + red2[8 * r + 1] + red2[8 * r + 2] + red2[8 * r + 3]
            + red2[8 * r + 4] + red2[8 * r + 5] + red2[8 * r + 6] + red2[8 * r + 7];
        float inv = sum > 0.f ? 1.f / sum : 0.f;
        *(float2*)&al[r][jb] = make_float2(ev[0] * inv, ev[1] * inv);
        if ((tid & 511) == 0) gsum[r] = sum;
    }
    __syncthreads();   // al + gsum + pdl/utl visible; no barriers until epilogue

    const int l16 = tid & 15, g = tid >> 4;        // 64 groups x 16 lanes
    const int k0a = l16 * 4, k0b = 64 + l16 * 4;
    const float4 wp0 = *(const float4*)&wpd[k0a];
    const float4 wp1 = *(const float4*)&wpd[k0b];
    const float4 wu0 = *(const float4*)&wut[k0a];
    const float4 wu1 = *(const float4*)&wut[k0b];

    float4 a0[MROWS] = {}, a1[MROWS] = {};

    #pragma unroll 2
    for (int c = 0; c < 16; c++) {
        int j = c * 64 + g;
        float4 b0  = *(const float4*)&base[j * D + k0a];
        float4 b1v = *(const float4*)&base[j * D + k0b];
        #pragma unroll
        for (int r = 0; r < MROWS; r++) {
            float spd = pdl[r][j];
            float sut = utl[r][j];
            float sal = al[r][j];
            float v;
            v = fmaxf(fmaf(spd, wp0.x, fmaf(sut, wu0.x, b0.x)), 0.f);  a0[r].x = fmaf(sal, v, a0[r].x);
            v = fmaxf(fmaf(spd, wp0.y, fmaf(sut, wu0.y, b0.y)), 0.f);  a0[r].y = fmaf(sal, v, a0[r].y);
            v = fmaxf(fmaf(spd, wp0.z, fmaf(sut, wu0.z, b0.z)), 0.f);  a0[r].z = fmaf(sal, v, a0[r].z);
            v = fmaxf(fmaf(spd, wp0.w, fmaf(sut, wu0.w, b0.w)), 0.f);  a0[r].w = fmaf(sal, v, a0[r].w);
            v = fmaxf(fmaf(spd, wp1.x, fmaf(sut, wu1.x, b1v.x)), 0.f); a1[r].x = fmaf(sal, v, a1[r].x);
            v = fmaxf(fmaf(spd, wp1.y, fmaf(sut, wu1.y, b1v.y)), 0.f); a1[r].y = fmaf(sal, v, a1[r].y);
            v = fmaxf(fmaf(spd, wp1.z, fmaf(sut, wu1.z, b1v.z)), 0.f); a1[r].z = fmaf(sal, v, a1[r].z);
            v = fmaxf(fmaf(spd, wp1.w, fmaf(sut, wu1.w, b1v.w)), 0.f); a1[r].w = fmaf(sal, v, a1[r].w);
        }
    }

    // ---- in-wave cross-group reduce: lanes l, l^16, l^32, l^48 share l16 ----
    #pragma unroll
    for (int r = 0; r < MROWS; r++) {
        #pragma unroll
        for (int m = 16; m <= 32; m <<= 1) {
            a0[r].x += __shfl_xor(a0[r].x, m); a0[r].y += __shfl_xor(a0[r].y, m);
            a0[r].z += __shfl_xor(a0[r].z, m); a0[r].w += __shfl_xor(a0[r].w, m);
            a1[r].x += __shfl_xor(a1[r].x, m); a1[r].y += __shfl_xor(a1[r].y, m);
            a1[r].z += __shfl_xor(a1[r].z, m); a1[r].w += __shfl_xor(a1[r].w, m);
        }
    }
    {
        int w = tid >> 6, lane = tid & 63;
        if (lane < 16) {
            #pragma unroll
            for (int r = 0; r < MROWS; r++) {
                *(float4*)&racc[w][r][k0a] = a0[r];
                *(float4*)&racc[w][r][k0b] = a1[r];
            }
        }
    }
    __syncthreads();
    if (tid < 256) {
        int rr = tid >> 7, k = tid & 127;
        float v = 0.f;
        #pragma unroll
        for (int w = 0; w < 16; w++) v += racc[w][rr][k];
        tl[rr][k] = v;
    }
    __syncthreads();
    // ---- final GEMM: out[i][d] = sum_k t[k] * W2t[k][d] + gate*b2[d] ----
    if (tid < 256) {
        int rr = tid >> 7, d = tid & 127;
        float acc = (gsum[rr] > 0.f) ? b2[d] : 0.f;
        #pragma unroll 8
        for (int k = 0; k < D; k++)
            acc = fmaf(tl[rr][k], W2t[k * D + d], acc);
        out[(i0 + rr) * D + d] = acc;
    }
}

// ---------------------------------------------------------------------------
extern "C" void kernel_launch(void* const* d_in, const int* in_sizes, int n_in,
                              void* d_out, int out_size, void* d_ws, size_t ws_size,
                              hipStream_t stream) {
    (void)in_sizes; (void)n_in; (void)out_size; (void)ws_size;
    const float* h   = (const float*)d_in[0];
    const int*   adj = (const int*)d_in[1];
    const float* pd  = (const float*)d_in[2];
    const float* ut  = (const float*)d_in[3];
    const float* W   = (const float*)d_in[4];
    const float* a   = (const float*)d_in[5];
    const float* W1  = (const float*)d_in[6];
    const float* b1  = (const float*)d_in[7];
    const float* W2  = (const float*)d_in[8];
    const float* b2  = (const float*)d_in[9];
    float* out = (float*)d_out;
    float* ws = (float*)d_ws;

    float* W2t   = ws + OFF_W2T;
    float* wpd   = ws + OFF_WPD;
    float* wut   = ws + OFF_WUT;
    float* s1    = ws + OFF_S1;
    float* s2    = ws + OFF_S2;
    float* baseb = ws + OFF_BASE;

    prep_base_kernel<<<517, 256, 0, stream>>>(W, W1, W2, a, h, b1,
                                              W2t, wpd, wut, s1, s2, baseb);
    mega_kernel<<<N / MROWS, 1024, 0, stream>>>(baseb, s1, s2, adj, pd, ut,
                                                wpd, wut, W2t, b2, out);
}